// Round 6
// baseline (292.223 us; speedup 1.0000x reference)
//
#include <hip/hip_runtime.h>
#include <hip/hip_bf16.h>

#define N_PTS 8192
#define KNN 8

typedef __attribute__((ext_vector_type(8))) short short8;
typedef __attribute__((ext_vector_type(4))) float float4v;
typedef __attribute__((ext_vector_type(16))) float f32x16;
typedef unsigned long long u64;

// f32 -> bf16 round-to-nearest-even (finite inputs only)
static __device__ __forceinline__ short f2bf(float f) {
    unsigned u = __float_as_uint(f);
    unsigned r = (u + 0x7FFFu + ((u >> 16) & 1u)) >> 16;
    return (short)r;
}
static __device__ __forceinline__ float bf2f(short s) {
    return __uint_as_float(((unsigned)(unsigned short)s) << 16);
}

// monotone float -> u32 key (handles negative d' = |c|^2 - 2 q.c)
static __device__ __forceinline__ unsigned sortkey(float f) {
    unsigned u = __float_as_uint(f);
    return u ^ (((unsigned)((int)u >> 31)) | 0x80000000u);
}

static __device__ __forceinline__ void ins8(u64* best, u64 x) {
#pragma unroll
    for (int j = 0; j < 8; ++j) {
        const u64 lo = x < best[j] ? x : best[j];
        const u64 hi = x < best[j] ? best[j] : x;
        best[j] = lo; x = hi;
    }
}

// VGPR-pinned min update (r5 win: stops AGPR demotion of persistent state).
static __device__ __forceinline__ void vmin_acc(float& acc, float d) {
    asm("v_min_f32 %0, %0, %1" : "+v"(acc) : "v"(d));
}
// VGPR-pinned compare-exchange for the insertion networks.
static __device__ __forceinline__ void vsort2(float& a, float& x) {
    float lo, hi;
    asm("v_min_f32 %0, %2, %3\n\tv_max_f32 %1, %2, %3"
        : "=&v"(lo), "=v"(hi) : "v"(a), "v"(x));
    a = lo; x = hi;
}

// Wave-uniform candidate fetch: 8 float4 candidates -> 32 SGPRs via two
// s_load_dwordx16 on the SCALAR pipe. r5 diagnosis: 1024 ds_read_b128 per
// thread = ~82 us of DS-pipe occupancy per CU == the measured 86 us wall.
// Candidate addresses are block-uniform, so this traffic belongs on SMEM.
// waitcnt fused in the same asm block => consumers are data-dependent on
// the asm outputs (no rule-18 hoisting hazard). volatile stops cross-pass
// CSE of the 128-float candidate window (would spill).
static __device__ __forceinline__ void sload8(const float4* p, f32x16& A_, f32x16& B_) {
    asm volatile("s_load_dwordx16 %0, %2, 0x0\n\t"
                 "s_load_dwordx16 %1, %2, 0x40\n\t"
                 "s_waitcnt lgkmcnt(0)"
                 : "=s"(A_), "=s"(B_)
                 : "s"(p));
}

// ---------------------------------------------------------------------------
// Dispatch 0: pack positions as (x, y, z, |c|^2) float4 so knn can stream
// candidates via scalar loads. |c|^2 formula bit-identical to the r5 LDS
// packer (selection invariant).
// ---------------------------------------------------------------------------
__global__ __launch_bounds__(256) void pack_pos(const float* __restrict__ pos,
                                                float4* __restrict__ packed)
{
    const int i = blockIdx.x * 256 + threadIdx.x;   // 0..16383
    const float x = pos[i * 3 + 0];
    const float y = pos[i * 3 + 1];
    const float z = pos[i * 3 + 2];
    packed[i] = make_float4(x, y, z, fmaf(x, x, fmaf(y, y, z * z)));
}

// ---------------------------------------------------------------------------
// Dispatch 1: knn_partial (1024 blocks) + all f32->bf16 conversions (4096
// blocks), 1:4 interleave (r1/r5 structure).
//
// knn (round 6): one query per thread, 16 partitions x 512 cand. Candidates
// streamed from packed[] via s_load_dwordx16 (scalar pipe) -- the DS pipe is
// freed entirely except the tiny collect buffer. Per-candidate math and
// selection identical to r5: d' = |c|^2 - 2 q.c; 32 rotating bucket minima
// (ASM-pinned VGPRs, compile-time bucket indices only); threshold = 8th
// smallest bucket min; exec-masked collect of u16 local indices (cap 16);
// exact top-8 over survivors (global gather, L2-hot); exact full-rescan
// fallback if cnt > 16 (statistically never).
// ---------------------------------------------------------------------------
__global__ __launch_bounds__(256) void fused_knn_conv(const float4* __restrict__ packed,
                                                      u64* __restrict__ partial,
                                                      const float* __restrict__ x,
                                                      const float* __restrict__ Wq,
                                                      const float* __restrict__ Wkv,
                                                      const float* __restrict__ Wout,
                                                      short* __restrict__ xb,
                                                      short* __restrict__ wqkvt,
                                                      short* __restrict__ woutt)
{
    __shared__ unsigned short buf[256 * 17];         // 8704 B (collect only)
    const int tid = threadIdx.x;
    const int g5 = blockIdx.x / 5;
    const int r5 = blockIdx.x % 5;

    if (r5 == 0) {
        // ================= KNN block (1024 total) =========================
        const int kb = g5;                           // 0..1023
        const int p   = kb & 15;
        const int qg  = kb >> 4;
        const int batch = qg >> 5;
        const int q_in_b = (qg & 31) * 256 + tid;

        const float4* __restrict__ cbase = packed + batch * N_PTS + p * 512;

        const float4 q4 = packed[batch * N_PTS + q_in_b];
        const float nqx = -2.0f * q4.x;
        const float nqy = -2.0f * q4.y;
        const float nqz = -2.0f * q4.z;

        // ---- pass 1: 32 rotating bucket minima (bucket = cand_idx & 31) --
        float bmin[32];
#pragma unroll
        for (int j = 0; j < 32; ++j) bmin[j] = 3.0e38f;

        for (int c32 = 0; c32 < 512; c32 += 32) {
#pragma unroll
            for (int sub = 0; sub < 32; sub += 8) {  // static after unroll
                f32x16 A_, B_;
                sload8(cbase + c32 + sub, A_, B_);
#pragma unroll
                for (int j = 0; j < 4; ++j) {
                    const float d0 = fmaf(A_[4*j], nqx,
                                     fmaf(A_[4*j+1], nqy,
                                     fmaf(A_[4*j+2], nqz, A_[4*j+3])));
                    vmin_acc(bmin[sub + j], d0);
                    const float d1 = fmaf(B_[4*j], nqx,
                                     fmaf(B_[4*j+1], nqy,
                                     fmaf(B_[4*j+2], nqz, B_[4*j+3])));
                    vmin_acc(bmin[sub + 4 + j], d1);
                }
            }
        }

        // ---- threshold = 8th smallest bucket min -------------------------
        float t8[8];
#pragma unroll
        for (int j = 0; j < 8; ++j) t8[j] = 3.0e38f;
#pragma unroll
        for (int i = 0; i < 32; ++i) {
            float x_ = bmin[i];
#pragma unroll
            for (int j = 0; j < 8; ++j)
                vsort2(t8[j], x_);
        }
        const float t = t8[7];

        // ---- pass 2: exec-masked threshold collect -----------------------
        int cnt = 0;
        for (int base = 0; base < 512; base += 8) {
            f32x16 A_, B_;
            sload8(cbase + base, A_, B_);
#pragma unroll
            for (int j = 0; j < 4; ++j) {
                const float d = fmaf(A_[4*j], nqx,
                                fmaf(A_[4*j+1], nqy,
                                fmaf(A_[4*j+2], nqz, A_[4*j+3])));
                if (d <= t) {
                    buf[tid * 17 + (cnt < 16 ? cnt : 16)] = (unsigned short)(base + j);
                    ++cnt;
                }
            }
#pragma unroll
            for (int j = 0; j < 4; ++j) {
                const float d = fmaf(B_[4*j], nqx,
                                fmaf(B_[4*j+1], nqy,
                                fmaf(B_[4*j+2], nqz, B_[4*j+3])));
                if (d <= t) {
                    buf[tid * 17 + (cnt < 16 ? cnt : 16)] = (unsigned short)(base + 4 + j);
                    ++cnt;
                }
            }
        }

        // ---- exact top-8 over survivors ----------------------------------
        u64 best[8];
#pragma unroll
        for (int j = 0; j < 8; ++j) best[j] = ~0ULL;

        if (cnt <= 16) {
            for (int u = 0; u < cnt; ++u) {
                const int i = buf[tid * 17 + u];
                const float4 c = cbase[i];           // per-lane gather (L2-hot)
                const float d = fmaf(c.x, nqx, fmaf(c.y, nqy, fmaf(c.z, nqz, c.w)));
                ins8(best, ((u64)sortkey(d) << 32) | (unsigned)(p * 512 + i));
            }
        } else {
            for (int i = 0; i < 512; ++i) {          // statistically-never fallback
                const float4 c = cbase[i];
                const float d = fmaf(c.x, nqx, fmaf(c.y, nqy, fmaf(c.z, nqz, c.w)));
                const u64 x_ = ((u64)sortkey(d) << 32) | (unsigned)(p * 512 + i);
                if (x_ < best[7]) ins8(best, x_);
            }
        }

        const long qglob = (long)batch * N_PTS + q_in_b;
#pragma unroll
        for (int j = 0; j < 8; ++j)
            partial[(long)(p * 8 + j) * 16384 + qglob] = best[j];   // coalesced

    } else {
        // ================= conv block (4096 total, LDS-free) ==============
        const int bid = g5 * 4 + (r5 - 1);           // 0..4095
        if (bid < 2048) {
            const int i = bid * 256 + tid;
            const float4 a = ((const float4*)x)[i * 2];
            const float4 b = ((const float4*)x)[i * 2 + 1];
            short8 w = {f2bf(a.x), f2bf(a.y), f2bf(a.z), f2bf(a.w),
                        f2bf(b.x), f2bf(b.y), f2bf(b.z), f2bf(b.w)};
            ((short8*)xb)[i] = w;
        } else if (bid < 2560) {
            const int o = (bid - 2048) * 256 + tid;  // n*256+k, n<512
            const int n = o >> 8, k = o & 255;
            wqkvt[o] = f2bf(Wq[(long)k * 512 + n]);
        } else if (bid < 3584) {
            const int o = (bid - 2560) * 256 + tid;  // n*256+k, n<1024
            const int n = o >> 8, k = o & 255;
            wqkvt[131072 + o] = f2bf(Wkv[(long)k * 1024 + n]);
        } else {
            const int o = (bid - 3584) * 256 + tid;  // n*512+k, n<256
            const int n = o >> 9, k = o & 511;
            woutt[o] = f2bf(Wout[(long)k * 256 + n]);
        }
    }
}

// ---------------------------------------------------------------------------
// Dispatch 2: q/kv GEMM (1536 blocks) + knn_merge (first 64 blocks).
// merge uses zero LDS; co-resident with the gemm flood it hides completely.
// gemm: xb[16384,256] x wqkvt[1536,256]^T, 128x128 tile, BK=32, 4 waves 2x2,
// 16x16x32 MFMA; cols [0,512) -> qall (stride 512), [512,1536) -> kvall.
// ---------------------------------------------------------------------------
__global__ __launch_bounds__(256) void fused_gemm_merge(const short* __restrict__ A,
                                                        const short* __restrict__ Bt,
                                                        short* __restrict__ qall,
                                                        short* __restrict__ kvall,
                                                        const u64* __restrict__ partial,
                                                        int* __restrict__ idxo)
{
    __shared__ short As[128][40];
    __shared__ short Bs[128][40];

    const int tid = threadIdx.x;

    if (blockIdx.x < 64) {
        // ================= merge block (zero LDS) =========================
        const int q = blockIdx.x * 256 + tid;
        u64 best[8];
#pragma unroll
        for (int j = 0; j < 8; ++j) best[j] = ~0ULL;
        for (int s = 0; s < 128; ++s) {
            u64 x = partial[(long)s * 16384 + q];
            if (x < best[7]) ins8(best, x);
        }
#pragma unroll
        for (int j = 0; j < 8; ++j)
            idxo[(long)q * 8 + j] = (int)(best[j] & 0xFFFFFFFFu);
        return;
    }

    // ================= GEMM block (1536 total) ============================
    const int id = blockIdx.x - 64;
    const int bx = id % 12;
    const int by = id / 12;

    const int lane = tid & 63;
    const int wv   = tid >> 6;
    const int quad = lane >> 4;
    const int l15  = lane & 15;
    const int m0 = by * 128;
    const int n0 = bx * 128;
    const int mh = (wv & 1) * 64, nh = (wv >> 1) * 64;

    const int srow  = tid >> 1;
    const int shalf = (tid & 1) * 16;
    const int Kd = 256;

    float4v acc[4][4];
#pragma unroll
    for (int i = 0; i < 4; ++i)
#pragma unroll
        for (int j = 0; j < 4; ++j) acc[i][j] = (float4v)(0.f);

    for (int k0 = 0; k0 < Kd; k0 += 32) {
        const short8* asrc = (const short8*)(A + (long)(m0 + srow) * Kd + k0 + shalf);
        const short8* bsrc = (const short8*)(Bt + (long)(n0 + srow) * Kd + k0 + shalf);
        *(short8*)&As[srow][shalf]     = asrc[0];
        *(short8*)&As[srow][shalf + 8] = asrc[1];
        *(short8*)&Bs[srow][shalf]     = bsrc[0];
        *(short8*)&Bs[srow][shalf + 8] = bsrc[1];
        __syncthreads();

        short8 af[4], bfv[4];
#pragma unroll
        for (int i = 0; i < 4; ++i)
            af[i] = *(const short8*)&As[mh + i * 16 + l15][quad * 8];
#pragma unroll
        for (int j = 0; j < 4; ++j)
            bfv[j] = *(const short8*)&Bs[nh + j * 16 + l15][quad * 8];
#pragma unroll
        for (int i = 0; i < 4; ++i)
#pragma unroll
            for (int j = 0; j < 4; ++j)
                acc[i][j] = __builtin_amdgcn_mfma_f32_16x16x32_bf16(af[i], bfv[j], acc[i][j], 0, 0, 0);
        __syncthreads();
    }

    short* Cb;
    int stride, cb;
    if (n0 < 512) { Cb = qall;  stride = 512;  cb = n0; }
    else          { Cb = kvall; stride = 1024; cb = n0 - 512; }

#pragma unroll
    for (int i = 0; i < 4; ++i)
#pragma unroll
        for (int j = 0; j < 4; ++j) {
            const int col = cb + nh + j * 16 + l15;
#pragma unroll
            for (int r = 0; r < 4; ++r) {
                const int row = m0 + mh + i * 16 + quad * 4 + r;
                Cb[(long)row * stride + col] = f2bf(acc[i][j][r]);
            }
        }
}

// ---------------------------------------------------------------------------
// Fused KNN attention, bf16 storage / f32 math (unchanged since round 5).
// ---------------------------------------------------------------------------
__global__ __launch_bounds__(256) void attn_kernel(const short* qall,
                                                   const short* __restrict__ kvall,
                                                   const int* __restrict__ idxp,
                                                   short* outp)
{
    __shared__ float attn_s[4][8][8];
    const int wave = threadIdx.x >> 6;
    const int lane = threadIdx.x & 63;
    const int g = blockIdx.x * 4 + wave;
    const int b = g >> 13;
    const int* myidx = idxp + (long)g * 8;

    {
        const int h = lane >> 3;
        const int k = lane & 7;
        const int j = myidx[k];
        const short8* qrow = (const short8*)(qall + (long)g * 512 + h * 64);
        const short8* krow = (const short8*)(kvall + ((long)(b * N_PTS + j)) * 1024 + h * 64);

        float dot = 0.f;
#pragma unroll
        for (int c = 0; c < 8; ++c) {
            const short8 qv = qrow[c];
            const short8 kv = krow[c];
#pragma unroll
            for (int e = 0; e < 8; ++e)
                dot = fmaf(bf2f(qv[e]), bf2f(kv[e]), dot);
        }
        dot *= 0.125f;

        float m = dot;
#pragma unroll
        for (int off = 1; off < 8; off <<= 1)
            m = fmaxf(m, __shfl_xor(m, off, 8));
        const float e = __expf(dot - m);
        float ssum = e;
#pragma unroll
        for (int off = 1; off < 8; off <<= 1)
            ssum += __shfl_xor(ssum, off, 8);
        attn_s[wave][h][k] = e / ssum;
    }
    __syncthreads();                      // drains q reads before aliased writes

    const int d8 = lane * 8;
    const int h2 = lane >> 3;
    float o[8] = {0.f, 0.f, 0.f, 0.f, 0.f, 0.f, 0.f, 0.f};
#pragma unroll
    for (int kk = 0; kk < 8; ++kk) {
        const int jj = myidx[kk];
        const float w = attn_s[wave][h2][kk];
        const short8 v = *(const short8*)(kvall + ((long)(b * N_PTS + jj)) * 1024 + 512 + d8);
#pragma unroll
        for (int e = 0; e < 8; ++e)
            o[e] = fmaf(w, bf2f(v[e]), o[e]);
    }
    short8 ov = {f2bf(o[0]), f2bf(o[1]), f2bf(o[2]), f2bf(o[3]),
                 f2bf(o[4]), f2bf(o[5]), f2bf(o[6]), f2bf(o[7])};
    *(short8*)(outp + (long)g * 512 + d8) = ov;
}

// ---------------------------------------------------------------------------
// Out-projection bf16 MFMA GEMM: C f32 = A[M,512] x Bt[256,512]^T + bias.
// ---------------------------------------------------------------------------
__global__ __launch_bounds__(256) void gemm_out(const short* __restrict__ A,
                                                const short* __restrict__ Bt,
                                                const float* __restrict__ bias,
                                                float* __restrict__ C,
                                                int N, int Kd)
{
    __shared__ short As[128][40];
    __shared__ short Bs[128][40];

    const int tid  = threadIdx.x;
    const int lane = tid & 63;
    const int wv   = tid >> 6;
    const int quad = lane >> 4;
    const int l15  = lane & 15;
    const int m0 = blockIdx.y * 128;
    const int n0 = blockIdx.x * 128;
    const int mh = (wv & 1) * 64, nh = (wv >> 1) * 64;

    const int srow  = tid >> 1;
    const int shalf = (tid & 1) * 16;

    float4v acc[4][4];
#pragma unroll
    for (int i = 0; i < 4; ++i)
#pragma unroll
        for (int j = 0; j < 4; ++j) acc[i][j] = (float4v)(0.f);

    for (int k0 = 0; k0 < Kd; k0 += 32) {
        const short8* asrc = (const short8*)(A + (long)(m0 + srow) * Kd + k0 + shalf);
        const short8* bsrc = (const short8*)(Bt + (long)(n0 + srow) * Kd + k0 + shalf);
        *(short8*)&As[srow][shalf]     = asrc[0];
        *(short8*)&As[srow][shalf + 8] = asrc[1];
        *(short8*)&Bs[srow][shalf]     = bsrc[0];
        *(short8*)&Bs[srow][shalf + 8] = bsrc[1];
        __syncthreads();

        short8 af[4], bfv[4];
#pragma unroll
        for (int i = 0; i < 4; ++i)
            af[i] = *(const short8*)&As[mh + i * 16 + l15][quad * 8];
#pragma unroll
        for (int j = 0; j < 4; ++j)
            bfv[j] = *(const short8*)&Bs[nh + j * 16 + l15][quad * 8];
#pragma unroll
        for (int i = 0; i < 4; ++i)
#pragma unroll
            for (int j = 0; j < 4; ++j)
                acc[i][j] = __builtin_amdgcn_mfma_f32_16x16x32_bf16(af[i], bfv[j], acc[i][j], 0, 0, 0);
        __syncthreads();
    }

#pragma unroll
    for (int i = 0; i < 4; ++i)
#pragma unroll
        for (int j = 0; j < 4; ++j) {
            const int col = n0 + nh + j * 16 + l15;
            const float bb = bias[col];
#pragma unroll
            for (int r = 0; r < 4; ++r) {
                const int row = m0 + mh + i * 16 + quad * 4 + r;
                C[(long)row * N + col] = acc[i][j][r] + bb;
            }
        }
}

// ---------------------------------------------------------------------------
extern "C" void kernel_launch(void* const* d_in, const int* in_sizes, int n_in,
                              void* d_out, int out_size, void* d_ws, size_t ws_size,
                              hipStream_t stream)
{
    const float* x    = (const float*)d_in[0];  // [2,8192,256]
    const float* pos  = (const float*)d_in[1];  // [2,8192,3]
    const float* Wq   = (const float*)d_in[2];  // [256,512]
    const float* Wkv  = (const float*)d_in[3];  // [256,1024]
    const float* Wout = (const float*)d_in[4];  // [512,256]
    const float* bout = (const float*)d_in[5];  // [256]
    float* out = (float*)d_out;                 // [2,8192,256] f32

    const int M = 16384;

    // workspace layout:
    char* ws = (char*)d_ws;
    int*   idxp  = (int*)ws;                          ws += 1 << 19;             // 512 KB
    short* qall  = (short*)ws;                        ws += (long)M * 512 * 2;   // 16 MB
    short* kvall = (short*)ws;                        ws += (long)M * 1024 * 2;  // 32 MB
    short* xb    = (short*)ws;                        ws += (long)M * 256 * 2;   // 8 MB
    short* wqkvt = (short*)ws;                        ws += 1536 * 256 * 2;      // 768 KB
    short* woutt = (short*)ws;                        ws += 256 * 512 * 2;       // 256 KB
    u64*  partial = (u64*)ws;                         ws += (long)128 * 16384 * 8; // 16 MB
    float4* packed = (float4*)ws;                     ws += (long)M * 16;        // 256 KB

    pack_pos<<<64, 256, 0, stream>>>(pos, packed);
    fused_knn_conv<<<5120, 256, 0, stream>>>(packed, partial, x, Wq, Wkv, Wout,
                                             xb, wqkvt, woutt);
    fused_gemm_merge<<<1600, 256, 0, stream>>>(xb, wqkvt, qall, kvall, partial, idxp);
    attn_kernel<<<M / 4, 256, 0, stream>>>(qall, kvall, idxp, qall);   // in-place
    gemm_out<<<dim3(2, 128), 256, 0, stream>>>(qall, woutt, bout, out, 256, 512);
}